// Round 8
// baseline (487.288 us; speedup 1.0000x reference)
//
#include <hip/hip_runtime.h>
#include <math.h>
#include <stdio.h>
#include <stdint.h>

#define GXD 272
#define GYD 112
#define GZD 272
#define NROT 36
#define CCLS (GXD*GZD)     /* 73984 = 289*256 */
#define KSMP 1024          /* NUM_PROPOSAL*OVERSAMPLE */
#define NPROP 256
#define HSLOTS 2048        /* sampled-cell hash table slots */
#define YH 56              /* y-half size */
#define NBINS (GXD*2)      /* 544: (x-slice, y-half) bins */
#define SLICE (GYD*GZD)    /* 30464 cells per x-slice */
#define SVCAP 64           /* survivor capacity per row (E~20) */
#define ROWG 8             /* row groups in prefilter grid */

struct RotTab { float c[NROT]; float s[NROT]; };

__device__ __forceinline__ uint32_t cell_hash(int flat) {
    return ((uint32_t)flat * 2654435761u) >> 21;  // top 11 bits -> 0..2047
}

// rotl via single v_alignbit_b32: alignbit(x,x,s) = rotr(x,s); rotl(x,r)=rotr(x,32-r)
#define ROTL_AB(x, r) __builtin_amdgcn_alignbit((x), (x), 32u - (r))

// ---------------- threefry2x32 (JAX semantics, 20 rounds) ----------------
__device__ __forceinline__ void threefry2x32(uint32_t k0, uint32_t k1,
                                             uint32_t x0, uint32_t x1,
                                             uint32_t& o0, uint32_t& o1) {
    uint32_t ks2 = k0 ^ k1 ^ 0x1BD11BDAu;
#define TF_ROUND(r) { x0 += x1; x1 = ROTL_AB(x1, r); x1 ^= x0; }
    x0 += k0; x1 += k1;
    TF_ROUND(13) TF_ROUND(15) TF_ROUND(26) TF_ROUND(6)
    x0 += k1;  x1 += ks2 + 1u;
    TF_ROUND(17) TF_ROUND(29) TF_ROUND(16) TF_ROUND(24)
    x0 += ks2; x1 += k0 + 2u;
    TF_ROUND(13) TF_ROUND(15) TF_ROUND(26) TF_ROUND(6)
    x0 += k0;  x1 += k1 + 3u;
    TF_ROUND(17) TF_ROUND(29) TF_ROUND(16) TF_ROUND(24)
    x0 += k1;  x1 += ks2 + 4u;
    TF_ROUND(13) TF_ROUND(15) TF_ROUND(26) TF_ROUND(6)
    x0 += ks2; x1 += k0 + 5u;
#undef TF_ROUND
    o0 = x0; o1 = x1;
}

// specialized: key (0,42), counter (0, i) -> o0^o1 (partitionable random_bits)
__device__ __forceinline__ uint32_t tf_bits(uint32_t i) {
    uint32_t o0, o1;
    threefry2x32(0u, 42u, 0u, i, o0, o1);
    return o0 ^ o1;
}

__device__ __forceinline__ float uniform_from_bits(uint32_t b) {
    const float TINY = 1.1754943508222875e-38f; // np.finfo(float32).tiny
    float f = __uint_as_float((b >> 9) | 0x3f800000u) - 1.0f;
    float u = __fadd_rn(__fmul_rn(f, 1.0f), TINY);
    return fmaxf(TINY, u);
}

// gumbel = -log(-log(u)); f32 logs via double rounding (== correctly-rounded logf)
__device__ __forceinline__ float gumbel_from_u(float u) {
    float l1 = (float)log((double)u);
    float l2 = (float)log((double)(-l1));
    return -l2;
}

// ---- vote voxel helpers: MUST stay bit-identical across all passes ----
__device__ __forceinline__ bool vote_iy(float py, float oy, float c0y, int& iy) {
    float ty = __fadd_rn(py, oy);
    float vy = __fadd_rn(__fdiv_rn(__fsub_rn(ty, c0y), 0.03f), 0.5f);
    iy = (int)floorf(vy);
    return (iy >= 0 && iy < GYD);
}
__device__ __forceinline__ bool vote_xz(float px, float pz, float ox, float oz,
                                        float c, float s, float c0x, float c0z,
                                        int& ix, int& iz) {
    float rx = __fadd_rn(__fmul_rn(ox, c), __fmul_rn(oz, s));
    float rz = __fadd_rn(__fmul_rn(-ox, s), __fmul_rn(oz, c));
    float tx = __fadd_rn(px, rx);
    float tz = __fadd_rn(pz, rz);
    float vx = __fadd_rn(__fdiv_rn(__fsub_rn(tx, c0x), 0.03f), 0.5f);
    float vz = __fadd_rn(__fdiv_rn(__fsub_rn(tz, c0z), 0.03f), 0.5f);
    ix = (int)floorf(vx);
    iz = (int)floorf(vz);
    return (ix >= 0 && ix < GXD && iz >= 0 && iz < GZD);
}
__device__ __forceinline__ bool vote_cell(float px, float py, float pz,
                                          float ox, float oy, float oz,
                                          float c, float s,
                                          float c0x, float c0y, float c0z,
                                          int& flat) {
    int iy, ix, iz;
    if (!vote_iy(py, oy, c0y, iy)) return false;
    if (!vote_xz(px, pz, ox, oz, c, s, c0x, c0z, ix, iz)) return false;
    flat = (ix*GYD + iy)*GZD + iz;
    return true;
}

// ---------------- K1a: count votes per (x-slice, y-half) bin ----------------
__global__ __launch_bounds__(256) void k_count(const float* __restrict__ pc, const float* __restrict__ xyz,
                          const float* __restrict__ corners, int N, RotTab rt,
                          int* __restrict__ bincnt) {
    __shared__ int h[NBINS];
    int tid = threadIdx.x;
    for (int j = tid; j < NBINS; j += 256) h[j] = 0;
    __syncthreads();
    int i = blockIdx.x * 256 + tid;
    if (i < N) {
        float px = pc[3*i], py = pc[3*i+1], pz = pc[3*i+2];
        float ox = xyz[3*i], oy = xyz[3*i+1], oz = xyz[3*i+2];
        int iy;
        if (vote_iy(py, oy, corners[1], iy)) {
            int ybit = (iy >= YH) ? 1 : 0;
            float c0x = corners[0], c0z = corners[2];
            for (int r = 0; r < NROT; ++r) {
                int ix, iz;
                if (vote_xz(px, pz, ox, oz, rt.c[r], rt.s[r], c0x, c0z, ix, iz))
                    atomicAdd(&h[ix*2 + ybit], 1);
            }
        }
    }
    __syncthreads();
    for (int j = tid; j < NBINS; j += 256) if (h[j]) atomicAdd(&bincnt[j], h[j]);
}

// ---------------- K1b: prefix sum over bins ----------------
__global__ void k_prefix(const int* __restrict__ bincnt, int* __restrict__ binbase,
                         int* __restrict__ bincur) {
    if (threadIdx.x == 0 && blockIdx.x == 0) {
        int acc = 0;
        for (int b = 0; b < NBINS; ++b) {
            binbase[b] = acc;
            bincur[b] = acc;
            acc += bincnt[b];
        }
    }
}

// ---------------- K1c: write vote records binned ----------------
__global__ __launch_bounds__(256) void k_binwrite(const float* __restrict__ pc, const float* __restrict__ xyz,
                          const float* __restrict__ prob, const float* __restrict__ corners,
                          int N, RotTab rt, int* __restrict__ bincur,
                          int* __restrict__ vflat, float* __restrict__ vw) {
    __shared__ int h[NBINS];
    __shared__ int bbase[NBINS];
    int tid = threadIdx.x;
    for (int j = tid; j < NBINS; j += 256) h[j] = 0;
    __syncthreads();
    int i = blockIdx.x * 256 + tid;
    float px=0, py=0, pz=0, ox=0, oy=0, oz=0, w0=0, c0x=0, c0z=0;
    int iy = -1, ybit = 0;
    bool act = false;
    if (i < N) {
        px = pc[3*i]; py = pc[3*i+1]; pz = pc[3*i+2];
        ox = xyz[3*i]; oy = xyz[3*i+1]; oz = xyz[3*i+2];
        w0 = prob[i];
        c0x = corners[0]; c0z = corners[2];
        if (vote_iy(py, oy, corners[1], iy)) {
            act = true;
            ybit = (iy >= YH) ? 1 : 0;
        }
    }
    if (act) {
        for (int r = 0; r < NROT; ++r) {
            int ix, iz;
            if (vote_xz(px, pz, ox, oz, rt.c[r], rt.s[r], c0x, c0z, ix, iz))
                atomicAdd(&h[ix*2 + ybit], 1);
        }
    }
    __syncthreads();
    for (int j = tid; j < NBINS; j += 256) {
        int cnt = h[j];
        bbase[j] = cnt ? atomicAdd(&bincur[j], cnt) : 0;
        h[j] = 0;  // reuse as local cursor
    }
    __syncthreads();
    if (act) {
        for (int r = 0; r < NROT; ++r) {
            int ix, iz;
            if (vote_xz(px, pz, ox, oz, rt.c[r], rt.s[r], c0x, c0z, ix, iz)) {
                int bin = ix*2 + ybit;
                int rank = atomicAdd(&h[bin], 1);
                int slot = bbase[bin] + rank;
                vflat[slot] = (ix*GYD + iy)*GZD + iz;
                vw[slot] = w0;
            }
        }
    }
}

// ---------------- K1d: per-bin LDS accumulate -> gobj ----------------
__global__ __launch_bounds__(256) void k_accum(const int* __restrict__ binbase,
                          const int* __restrict__ bincnt,
                          const int* __restrict__ vflat, const float* __restrict__ vw,
                          float* __restrict__ gobj) {
    __shared__ float tile[YH*GZD];   // 56*272*4 = 60928 B
    int b = blockIdx.x;
    int x = b >> 1, yh = b & 1;
    int tid = threadIdx.x;
    for (int j = tid; j < YH*GZD; j += 256) tile[j] = 0.0f;
    __syncthreads();
    int lo = binbase[b], n = bincnt[b];
    int xoff = x * SLICE;
    int yoff = yh * (YH*GZD);
    for (int j = lo + tid; j < lo + n; j += 256) {
        int rel = vflat[j] - xoff;        // (iy*GZD + iz) within slice
        atomicAdd(&tile[rel - yoff], vw[j]);
    }
    __syncthreads();
    float* dst = gobj + (size_t)xoff + yoff;
    for (int j = tid; j < YH*GZD; j += 256) dst[j] = tile[j];
}

// ---------------- K2: per-(x,z) max/argmax over y; logits; sum(dist) ----------------
__global__ __launch_bounds__(256) void k_colmax(const float* __restrict__ gobj,
                         float* __restrict__ logits, int* __restrict__ yidx,
                         float* __restrict__ sumdist) {
    int c = blockIdx.x * blockDim.x + threadIdx.x;
    float d = 0.0f;
    if (c < CCLS) {
        int x = c / GZD, z = c % GZD;
        const float* base = gobj + (size_t)x*GYD*GZD + z;
        float m = base[0];
        int mi = 0;
        for (int y = 1; y < GYD; ++y) {
            float v = base[(size_t)y*GZD];
            if (v > m) { m = v; mi = y; }  // strict > => first occurrence
        }
        d = __fsqrt_rn(__fadd_rn(m, 1e-7f));
        yidx[c] = mi;
        logits[c] = (float)log((double)__fadd_rn(d, 1e-30f));
    }
    __shared__ float sred[256];
    int tid = threadIdx.x;
    sred[tid] = d; __syncthreads();
    for (int off = 128; off > 0; off >>= 1) {
        if (tid < off) sred[tid] += sred[tid+off];
        __syncthreads();
    }
    if (tid == 0) atomicAdd(sumdist, sred[0]);
}

// ---------------- K2b: per-column integer bits-threshold ----------------
// survivor v = gumbel(u)+L > B0  <=>  u > u* = exp(-exp(L-B0)).  u = (bits>>9)*2^-23
// (monotone in bits).  Store bth = (floor(u*·2^23)-2)<<9: test (bits >= bth) can
// only OVER-include vs the exact condition (margin 2 mantissa steps + 0.05 in B0).
__global__ __launch_bounds__(256) void k_thresh(const float* __restrict__ logits,
                                                const float* __restrict__ sumdist,
                                                uint32_t* __restrict__ bth) {
    int c = blockIdx.x * blockDim.x + threadIdx.x;
    if (c >= CCLS) return;
    double B0 = log((double)*sumdist) - 3.0;
    double t = exp(-exp((double)logits[c] - (B0 - 0.05)));
    long long k_th = (long long)floor(t * 8388608.0) - 2;
    uint32_t b;
    if (k_th <= 0)              b = 0u;           // everything survives
    else if (k_th >= 8388608LL) b = 0xFFFFFFFFu;  // ~nothing survives (over-include, harmless)
    else                        b = (uint32_t)k_th << 9;
    bth[c] = b;
}

// ---------------- K3: prefilter — one thread per column, rows in registers ----------------
// grid (289, ROWG): thread owns column c = bx*256+tid, iterates 1024/ROWG rows.
// Hot loop: i += CCLS; threefry; compare vs in-register threshold. No memory ops.
__global__ __launch_bounds__(256) void k_prefilter(const uint32_t* __restrict__ bth,
                                                   int* __restrict__ svcnt,
                                                   uint2* __restrict__ svrec) {
    int c = blockIdx.x * 256 + threadIdx.x;   // 289*256 == CCLS exactly
    int k0 = blockIdx.y * (KSMP / ROWG);
    uint32_t th = bth[c];
    uint32_t i = (uint32_t)k0 * (uint32_t)CCLS + (uint32_t)c;
#pragma unroll 4
    for (int kk = 0; kk < KSMP / ROWG; ++kk) {
        uint32_t bits = tf_bits(i);
        if (__builtin_expect(bits >= th, 0)) {
            int row = k0 + kk;
            int idx = atomicAdd(&svcnt[row], 1);
            if (idx < SVCAP) svrec[row * SVCAP + idx] = make_uint2((uint32_t)c, bits);
        }
        i += (uint32_t)CCLS;
    }
}

// ---------------- K3f: per-row exact eval + argmax (fallback: full scan) ----------------
__global__ __launch_bounds__(256) void k_finalize(const float* __restrict__ logits,
                                                  const int* __restrict__ svcnt,
                                                  const uint2* __restrict__ svrec,
                                                  int* __restrict__ samples) {
    int k = blockIdx.x;
    int tid = threadIdx.x;
    int n = svcnt[k];
    float best = -INFINITY; int bc = 0x7fffffff;
    if (n > 0 && n <= SVCAP) {
        if (tid < n) {
            uint2 rec = svrec[k * SVCAP + tid];
            int c = (int)rec.x;
            best = __fadd_rn(gumbel_from_u(uniform_from_bits(rec.y)), logits[c]);
            bc = c;
        }
    } else {
        // empty (P ~ exp(-e^3)) or overflow (P ~ Poisson(20) tail @64): exact full scan
        uint32_t base = (uint32_t)k * (uint32_t)CCLS;
        for (int c = tid; c < CCLS; c += 256) {
            float v = __fadd_rn(gumbel_from_u(uniform_from_bits(tf_bits(base + (uint32_t)c))), logits[c]);
            if (v > best || (v == best && c < bc)) { best = v; bc = c; }
        }
    }
    __shared__ float sv[256];
    __shared__ int   si[256];
    sv[tid] = best; si[tid] = bc; __syncthreads();
    for (int off = 128; off > 0; off >>= 1) {
        if (tid < off) {
            float v2 = sv[tid+off]; int i2 = si[tid+off];
            if (v2 > sv[tid] || (v2 == sv[tid] && i2 < si[tid])) { sv[tid] = v2; si[tid] = i2; }
        }
        __syncthreads();
    }
    if (tid == 0) samples[k] = si[0];
}

// ---------------- K3b: build sampled-cell hash table (single block) ----------------
__global__ __launch_bounds__(256) void k_build_table(const int* __restrict__ samples,
                                                     const int* __restrict__ yidx,
                                                     int* __restrict__ hkeys,
                                                     float* __restrict__ gsmall) {
    int tid = threadIdx.x;
    for (int j = tid; j < HSLOTS; j += 256) hkeys[j] = -1;
    for (int j = tid; j < 3*HSLOTS; j += 256) gsmall[j] = 0.0f;
    __syncthreads();
    for (int k = tid; k < KSMP; k += 256) {
        int s = samples[k];
        int xi = s / GZD, zi = s % GZD;
        int yi = yidx[s];
        int flat = (xi*GYD + yi)*GZD + zi;
        uint32_t h = cell_hash(flat);
        for (;;) {
            int prev = atomicCAS(&hkeys[h], -1, flat);
            if (prev == -1 || prev == flat) break;
            h = (h + 1) & (HSLOTS - 1);
        }
    }
}

// ---------------- K3c: replay votes, accumulate scale sums at sampled cells ----------------
__global__ __launch_bounds__(256) void k_scale_scatter(const float* __restrict__ pc, const float* __restrict__ xyz,
                          const float* __restrict__ scale, const float* __restrict__ prob,
                          const float* __restrict__ corners,
                          const int* __restrict__ hkeys, float* __restrict__ gsmall,
                          int N, RotTab rt) {
    __shared__ int lk[HSLOTS];
    for (int j = threadIdx.x; j < HSLOTS; j += 256) lk[j] = hkeys[j];
    __syncthreads();
    int i = blockIdx.x * blockDim.x + threadIdx.x;
    int r = blockIdx.y;
    if (i >= N) return;
    int flat;
    if (!vote_cell(pc[3*i], pc[3*i+1], pc[3*i+2], xyz[3*i], xyz[3*i+1], xyz[3*i+2],
                   rt.c[r], rt.s[r], corners[0], corners[1], corners[2], flat)) return;
    uint32_t h = cell_hash(flat);
    int slot = -1;
    for (;;) {
        int key = lk[h];
        if (key == flat) { slot = (int)h; break; }
        if (key == -1) break;
        h = (h + 1) & (HSLOTS - 1);
    }
    if (slot < 0) return;
    float w0 = prob[i];
    atomicAdd(&gsmall[3*slot+0], __fmul_rn(w0, scale[3*i]));
    atomicAdd(&gsmall[3*slot+1], __fmul_rn(w0, scale[3*i+1]));
    atomicAdd(&gsmall[3*slot+2], __fmul_rn(w0, scale[3*i+2]));
}

// ---------------- K4: one block per sample — world loc, scale, keep ----------------
__global__ __launch_bounds__(256) void k_post(const float* __restrict__ gobj,
                       const int* __restrict__ hkeys, const float* __restrict__ gsmall,
                       const int* __restrict__ yidx, const int* __restrict__ samples,
                       const float* __restrict__ corners, const float* __restrict__ vp, int M,
                       float* __restrict__ world, float* __restrict__ scv, int* __restrict__ keep) {
    int k = blockIdx.x;
    int tid = threadIdx.x;
    int s = samples[k];
    int xi = s / GZD, zi = s % GZD;
    int yi = yidx[s];
    float wx = __fadd_rn(__fmul_rn((float)xi, 0.03f), corners[0]);
    float wy = __fadd_rn(__fmul_rn((float)yi, 0.03f), corners[1]);
    float wz = __fadd_rn(__fmul_rn((float)zi, 0.03f), corners[2]);

    float dmin = INFINITY;
    for (int j = tid; j < M; j += 256) {
        float dx = __fsub_rn(wx, vp[3*j]);
        float dy = __fsub_rn(wy, vp[3*j+1]);
        float dz = __fsub_rn(wz, vp[3*j+2]);
        float sq = __fadd_rn(__fadd_rn(__fmul_rn(dx,dx), __fmul_rn(dy,dy)), __fmul_rn(dz,dz));
        dmin = fminf(dmin, __fsqrt_rn(sq));
    }
    __shared__ float sm[256];
    sm[tid] = dmin; __syncthreads();
    for (int off = 128; off > 0; off >>= 1) {
        if (tid < off) sm[tid] = fminf(sm[tid], sm[tid+off]);
        __syncthreads();
    }
    if (tid == 0) {
        world[3*k] = wx; world[3*k+1] = wy; world[3*k+2] = wz;
        int flat = (xi*GYD + yi)*GZD + zi;
        uint32_t h = cell_hash(flat);
        while (hkeys[h] != flat) h = (h + 1) & (HSLOTS - 1);  // guaranteed present
        float go = __fadd_rn(gobj[flat], 1e-7f);
        scv[3*k+0] = __fdiv_rn(gsmall[3*h+0], go);
        scv[3*k+1] = __fdiv_rn(gsmall[3*h+1], go);
        scv[3*k+2] = __fdiv_rn(gsmall[3*h+2], go);
        keep[k] = (sm[0] < 0.3f) ? 1 : 0;
    }
}

// ---------------- K5: stable 0/1 selection + output write ----------------
__global__ __launch_bounds__(256) void k_select(const float* __restrict__ world,
                                                const float* __restrict__ scv,
                                                const int* __restrict__ keep,
                                                float* __restrict__ out) {
    __shared__ int kp[KSMP];
    __shared__ int sel[NPROP];
    int tid = threadIdx.x;
    for (int j = tid; j < KSMP; j += 256) kp[j] = keep[j];
    __syncthreads();
    if (tid == 0) {
        int any = 0;
        for (int j = 0; j < KSMP; ++j) any |= kp[j];
        int cnt = 0;
        if (any) {
            for (int j = 0; j < KSMP && cnt < NPROP; ++j) if (kp[j])  sel[cnt++] = j;
            for (int j = 0; j < KSMP && cnt < NPROP; ++j) if (!kp[j]) sel[cnt++] = j;
        } else {
            for (int j = 0; j < NPROP; ++j) sel[j] = j;  // argsort(zeros) stable = identity
        }
    }
    __syncthreads();
    if (tid < NPROP) {
        int sidx = sel[tid];
        out[3*tid+0] = world[3*sidx+0];
        out[3*tid+1] = world[3*sidx+1];
        out[3*tid+2] = world[3*sidx+2];
        out[3*NPROP + tid] = 0.0f;                 // probs
        out[4*NPROP + 3*tid + 0] = scv[3*sidx+0];
        out[4*NPROP + 3*tid + 1] = scv[3*sidx+1];
        out[4*NPROP + 3*tid + 2] = scv[3*sidx+2];
    }
}

extern "C" void kernel_launch(void* const* d_in, const int* in_sizes, int n_in,
                              void* d_out, int out_size, void* d_ws, size_t ws_size,
                              hipStream_t stream) {
    const float* pc      = (const float*)d_in[0];
    const float* xyz     = (const float*)d_in[1];
    const float* scale   = (const float*)d_in[2];
    const float* prob    = (const float*)d_in[3];
    const float* corners = (const float*)d_in[4];
    const float* vp      = (const float*)d_in[5];
    int N = in_sizes[0] / 3;
    int M = in_sizes[5] / 3;
    int NV = N * NROT;

    const size_t G = (size_t)GXD * GYD * GZD;  // 8,286,208
    float* gobj    = (float*)d_ws;
    float* sumdist = gobj + G;              // 1 float   — zeroed below
    int*   bincnt  = (int*)(sumdist + 1);   // NBINS     — zeroed below
    int*   svcnt   = bincnt + NBINS;        // KSMP      — zeroed below
    int*   binbase = svcnt + KSMP;
    int*   bincur  = binbase + NBINS;
    float* logits  = (float*)(bincur + NBINS);
    uint32_t* bth  = (uint32_t*)(logits + CCLS);
    int*   yidx    = (int*)(bth + CCLS);
    int*   samples = yidx + CCLS;
    int*   hkeys   = samples + KSMP;
    float* gsmall  = (float*)(hkeys + HSLOTS);
    float* world   = gsmall + 3*HSLOTS;
    float* scv     = world + 3*KSMP;
    int*   keep    = (int*)(scv + 3*KSMP);
    uint2* svrec   = (uint2*)(((uintptr_t)(keep + KSMP) + 15) & ~(uintptr_t)15);
    int*   vflat   = (int*)(svrec + (size_t)KSMP * SVCAP);
    float* vw      = (float*)(vflat + NV);
    size_t need = (size_t)((char*)(vw + NV) - (char*)d_ws);
    if (ws_size < need) {
        fprintf(stderr, "kernel_launch: ws_size %zu < needed %zu\n", ws_size, need);
        return;
    }

    // zero sumdist + bincnt + svcnt (contiguous; gobj fully written by k_accum)
    hipMemsetAsync(sumdist, 0, (1 + NBINS + KSMP)*sizeof(int), stream);

    // rotation table: f32 theta chain exactly as reference, cos/sin in double -> f32
    RotTab rt;
    const float twopi = (float)(2.0 * M_PI);
    for (int r = 0; r < NROT; ++r) {
        float th = (twopi * (float)r) / 36.0f;
        rt.c[r] = (float)cos((double)th);
        rt.s[r] = (float)sin((double)th);
    }

    int pblocks = (N + 255) / 256;
    k_count<<<pblocks, 256, 0, stream>>>(pc, xyz, corners, N, rt, bincnt);
    k_prefix<<<1, 64, 0, stream>>>(bincnt, binbase, bincur);
    k_binwrite<<<pblocks, 256, 0, stream>>>(pc, xyz, prob, corners, N, rt, bincur, vflat, vw);
    k_accum<<<NBINS, 256, 0, stream>>>(binbase, bincnt, vflat, vw, gobj);
    k_colmax<<<(CCLS + 255) / 256, 256, 0, stream>>>(gobj, logits, yidx, sumdist);
    k_thresh<<<(CCLS + 255) / 256, 256, 0, stream>>>(logits, sumdist, bth);
    dim3 pf_grid(CCLS / 256, ROWG);
    k_prefilter<<<pf_grid, 256, 0, stream>>>(bth, svcnt, svrec);
    k_finalize<<<KSMP, 256, 0, stream>>>(logits, svcnt, svrec, samples);
    k_build_table<<<1, 256, 0, stream>>>(samples, yidx, hkeys, gsmall);
    dim3 sgrid(pblocks, NROT);
    k_scale_scatter<<<sgrid, 256, 0, stream>>>(pc, xyz, scale, prob, corners, hkeys, gsmall, N, rt);
    k_post<<<KSMP, 256, 0, stream>>>(gobj, hkeys, gsmall, yidx, samples, corners, vp, M, world, scv, keep);
    k_select<<<1, 256, 0, stream>>>(world, scv, keep, (float*)d_out);
}

// Round 9
// 422.216 us; speedup vs baseline: 1.1541x; 1.1541x over previous
//
#include <hip/hip_runtime.h>
#include <math.h>
#include <stdio.h>
#include <stdint.h>

#define GXD 272
#define GYD 112
#define GZD 272
#define NROT 36
#define CCLS (GXD*GZD)     /* 73984 = 289*256 */
#define KSMP 1024          /* NUM_PROPOSAL*OVERSAMPLE */
#define NPROP 256
#define HSLOTS 2048        /* sampled-cell hash table slots */
#define YH 56              /* y-half size */
#define NBINS (GXD*2)      /* 544: (x-slice, y-half) bins */
#define SLICE (GYD*GZD)    /* 30464 cells per x-slice */
#define SVCAP 64           /* survivor capacity per row (E~21) */
#define ROWG 16            /* row groups in prefilter grid */

struct RotTab { float c[NROT]; float s[NROT]; };

__device__ __forceinline__ uint32_t cell_hash(int flat) {
    return ((uint32_t)flat * 2654435761u) >> 21;  // top 11 bits -> 0..2047
}

// rotl via single v_alignbit_b32: alignbit(x,x,s) = rotr(x,s); rotl(x,r)=rotr(x,32-r)
#define ROTL_AB(x, r) __builtin_amdgcn_alignbit((x), (x), 32u - (r))

// ---------------- threefry2x32 (JAX semantics, 20 rounds) ----------------
__device__ __forceinline__ void threefry2x32(uint32_t k0, uint32_t k1,
                                             uint32_t x0, uint32_t x1,
                                             uint32_t& o0, uint32_t& o1) {
    uint32_t ks2 = k0 ^ k1 ^ 0x1BD11BDAu;
#define TF_ROUND(r) { x0 += x1; x1 = ROTL_AB(x1, r); x1 ^= x0; }
    x0 += k0; x1 += k1;
    TF_ROUND(13) TF_ROUND(15) TF_ROUND(26) TF_ROUND(6)
    x0 += k1;  x1 += ks2 + 1u;
    TF_ROUND(17) TF_ROUND(29) TF_ROUND(16) TF_ROUND(24)
    x0 += ks2; x1 += k0 + 2u;
    TF_ROUND(13) TF_ROUND(15) TF_ROUND(26) TF_ROUND(6)
    x0 += k0;  x1 += k1 + 3u;
    TF_ROUND(17) TF_ROUND(29) TF_ROUND(16) TF_ROUND(24)
    x0 += k1;  x1 += ks2 + 4u;
    TF_ROUND(13) TF_ROUND(15) TF_ROUND(26) TF_ROUND(6)
    x0 += ks2; x1 += k0 + 5u;
#undef TF_ROUND
    o0 = x0; o1 = x1;
}

// specialized: key (0,42), counter (0, i) -> o0^o1 (partitionable random_bits)
__device__ __forceinline__ uint32_t tf_bits(uint32_t i) {
    uint32_t o0, o1;
    threefry2x32(0u, 42u, 0u, i, o0, o1);
    return o0 ^ o1;
}

__device__ __forceinline__ float uniform_from_bits(uint32_t b) {
    const float TINY = 1.1754943508222875e-38f; // np.finfo(float32).tiny
    float f = __uint_as_float((b >> 9) | 0x3f800000u) - 1.0f;
    float u = __fadd_rn(__fmul_rn(f, 1.0f), TINY);
    return fmaxf(TINY, u);
}

// gumbel = -log(-log(u)); f32 logs via double rounding (== correctly-rounded logf)
__device__ __forceinline__ float gumbel_from_u(float u) {
    float l1 = (float)log((double)u);
    float l2 = (float)log((double)(-l1));
    return -l2;
}

// ---- vote voxel helpers: MUST stay bit-identical across all passes ----
__device__ __forceinline__ bool vote_iy(float py, float oy, float c0y, int& iy) {
    float ty = __fadd_rn(py, oy);
    float vy = __fadd_rn(__fdiv_rn(__fsub_rn(ty, c0y), 0.03f), 0.5f);
    iy = (int)floorf(vy);
    return (iy >= 0 && iy < GYD);
}
__device__ __forceinline__ bool vote_xz(float px, float pz, float ox, float oz,
                                        float c, float s, float c0x, float c0z,
                                        int& ix, int& iz) {
    float rx = __fadd_rn(__fmul_rn(ox, c), __fmul_rn(oz, s));
    float rz = __fadd_rn(__fmul_rn(-ox, s), __fmul_rn(oz, c));
    float tx = __fadd_rn(px, rx);
    float tz = __fadd_rn(pz, rz);
    float vx = __fadd_rn(__fdiv_rn(__fsub_rn(tx, c0x), 0.03f), 0.5f);
    float vz = __fadd_rn(__fdiv_rn(__fsub_rn(tz, c0z), 0.03f), 0.5f);
    ix = (int)floorf(vx);
    iz = (int)floorf(vz);
    return (ix >= 0 && ix < GXD && iz >= 0 && iz < GZD);
}
__device__ __forceinline__ bool vote_cell(float px, float py, float pz,
                                          float ox, float oy, float oz,
                                          float c, float s,
                                          float c0x, float c0y, float c0z,
                                          int& flat) {
    int iy, ix, iz;
    if (!vote_iy(py, oy, c0y, iy)) return false;
    if (!vote_xz(px, pz, ox, oz, c, s, c0x, c0z, ix, iz)) return false;
    flat = (ix*GYD + iy)*GZD + iz;
    return true;
}

// ---------------- K1a: count votes per (x-slice, y-half) bin ----------------
__global__ __launch_bounds__(256) void k_count(const float* __restrict__ pc, const float* __restrict__ xyz,
                          const float* __restrict__ corners, int N, RotTab rt,
                          int* __restrict__ bincnt) {
    __shared__ int h[NBINS];
    int tid = threadIdx.x;
    for (int j = tid; j < NBINS; j += 256) h[j] = 0;
    __syncthreads();
    int i = blockIdx.x * 256 + tid;
    if (i < N) {
        float px = pc[3*i], py = pc[3*i+1], pz = pc[3*i+2];
        float ox = xyz[3*i], oy = xyz[3*i+1], oz = xyz[3*i+2];
        int iy;
        if (vote_iy(py, oy, corners[1], iy)) {
            int ybit = (iy >= YH) ? 1 : 0;
            float c0x = corners[0], c0z = corners[2];
            for (int r = 0; r < NROT; ++r) {
                int ix, iz;
                if (vote_xz(px, pz, ox, oz, rt.c[r], rt.s[r], c0x, c0z, ix, iz))
                    atomicAdd(&h[ix*2 + ybit], 1);
            }
        }
    }
    __syncthreads();
    for (int j = tid; j < NBINS; j += 256) if (h[j]) atomicAdd(&bincnt[j], h[j]);
}

// ---------------- K1b: parallel exclusive scan over 544 bins ----------------
__global__ __launch_bounds__(576) void k_prefix(const int* __restrict__ bincnt,
                         int* __restrict__ binbase, int* __restrict__ bincur) {
    __shared__ int sc[576];
    int tid = threadIdx.x;
    int v = (tid < NBINS) ? bincnt[tid] : 0;
    sc[tid] = v;
    __syncthreads();
    for (int off = 1; off < 576; off <<= 1) {
        int x = sc[tid];
        if (tid >= off) x += sc[tid - off];
        __syncthreads();
        sc[tid] = x;
        __syncthreads();
    }
    if (tid < NBINS) {
        int excl = sc[tid] - v;
        binbase[tid] = excl;
        bincur[tid] = excl;
    }
}

// ---------------- K1c: write vote records binned ----------------
__global__ __launch_bounds__(256) void k_binwrite(const float* __restrict__ pc, const float* __restrict__ xyz,
                          const float* __restrict__ prob, const float* __restrict__ corners,
                          int N, RotTab rt, int* __restrict__ bincur,
                          int* __restrict__ vflat, float* __restrict__ vw) {
    __shared__ int h[NBINS];
    __shared__ int bbase[NBINS];
    int tid = threadIdx.x;
    for (int j = tid; j < NBINS; j += 256) h[j] = 0;
    __syncthreads();
    int i = blockIdx.x * 256 + tid;
    float px=0, py=0, pz=0, ox=0, oy=0, oz=0, w0=0, c0x=0, c0z=0;
    int iy = -1, ybit = 0;
    bool act = false;
    if (i < N) {
        px = pc[3*i]; py = pc[3*i+1]; pz = pc[3*i+2];
        ox = xyz[3*i]; oy = xyz[3*i+1]; oz = xyz[3*i+2];
        w0 = prob[i];
        c0x = corners[0]; c0z = corners[2];
        if (vote_iy(py, oy, corners[1], iy)) {
            act = true;
            ybit = (iy >= YH) ? 1 : 0;
        }
    }
    if (act) {
        for (int r = 0; r < NROT; ++r) {
            int ix, iz;
            if (vote_xz(px, pz, ox, oz, rt.c[r], rt.s[r], c0x, c0z, ix, iz))
                atomicAdd(&h[ix*2 + ybit], 1);
        }
    }
    __syncthreads();
    for (int j = tid; j < NBINS; j += 256) {
        int cnt = h[j];
        bbase[j] = cnt ? atomicAdd(&bincur[j], cnt) : 0;
        h[j] = 0;  // reuse as local cursor
    }
    __syncthreads();
    if (act) {
        for (int r = 0; r < NROT; ++r) {
            int ix, iz;
            if (vote_xz(px, pz, ox, oz, rt.c[r], rt.s[r], c0x, c0z, ix, iz)) {
                int bin = ix*2 + ybit;
                int rank = atomicAdd(&h[bin], 1);
                int slot = bbase[bin] + rank;
                vflat[slot] = (ix*GYD + iy)*GZD + iz;
                vw[slot] = w0;
            }
        }
    }
}

// ---------------- K1d: per-bin LDS accumulate -> gobj ----------------
__global__ __launch_bounds__(256) void k_accum(const int* __restrict__ binbase,
                          const int* __restrict__ bincnt,
                          const int* __restrict__ vflat, const float* __restrict__ vw,
                          float* __restrict__ gobj) {
    __shared__ float tile[YH*GZD];   // 56*272*4 = 60928 B
    int b = blockIdx.x;
    int x = b >> 1, yh = b & 1;
    int tid = threadIdx.x;
    for (int j = tid; j < YH*GZD; j += 256) tile[j] = 0.0f;
    __syncthreads();
    int lo = binbase[b], n = bincnt[b];
    int xoff = x * SLICE;
    int yoff = yh * (YH*GZD);
    for (int j = lo + tid; j < lo + n; j += 256) {
        int rel = vflat[j] - xoff;        // (iy*GZD + iz) within slice
        atomicAdd(&tile[rel - yoff], vw[j]);
    }
    __syncthreads();
    float* dst = gobj + (size_t)xoff + yoff;
    for (int j = tid; j < YH*GZD; j += 256) dst[j] = tile[j];
}

// ---------------- K2: per-(x,z) max/argmax over y; logits; sum(dist) ----------------
__global__ __launch_bounds__(256) void k_colmax(const float* __restrict__ gobj,
                         float* __restrict__ logits, int* __restrict__ yidx,
                         float* __restrict__ sumdist) {
    int c = blockIdx.x * blockDim.x + threadIdx.x;
    float d = 0.0f;
    if (c < CCLS) {
        int x = c / GZD, z = c % GZD;
        const float* base = gobj + (size_t)x*GYD*GZD + z;
        float m = base[0];
        int mi = 0;
        for (int y = 1; y < GYD; ++y) {
            float v = base[(size_t)y*GZD];
            if (v > m) { m = v; mi = y; }  // strict > => first occurrence
        }
        d = __fsqrt_rn(__fadd_rn(m, 1e-7f));
        yidx[c] = mi;
        logits[c] = (float)log((double)__fadd_rn(d, 1e-30f));
    }
    __shared__ float sred[256];
    int tid = threadIdx.x;
    sred[tid] = d; __syncthreads();
    for (int off = 128; off > 0; off >>= 1) {
        if (tid < off) sred[tid] += sred[tid+off];
        __syncthreads();
    }
    if (tid == 0) atomicAdd(sumdist, sred[0]);
}

// ---------------- K2b: per-column integer bits-threshold ----------------
// survivor v = gumbel(u)+L > B0  <=>  u > u* = exp(-exp(L-B0)).  u = (bits>>9)*2^-23
// (monotone in bits).  Store bth = (floor(u*·2^23)-2)<<9: test (bits >= bth) can
// only OVER-include vs the exact condition (margin 2 mantissa steps + 0.05 in B0).
__global__ __launch_bounds__(256) void k_thresh(const float* __restrict__ logits,
                                                const float* __restrict__ sumdist,
                                                uint32_t* __restrict__ bth) {
    int c = blockIdx.x * blockDim.x + threadIdx.x;
    if (c >= CCLS) return;
    double B0 = log((double)*sumdist) - 3.0;
    double t = exp(-exp((double)logits[c] - (B0 - 0.05)));
    long long k_th = (long long)floor(t * 8388608.0) - 2;
    uint32_t b;
    if (k_th <= 0)              b = 0u;           // everything survives
    else if (k_th >= 8388608LL) b = 0xFFFFFFFFu;  // ~nothing survives (over-include, harmless)
    else                        b = (uint32_t)k_th << 9;
    bth[c] = b;
}

// ---------------- K3: prefilter — one thread per column, rows in registers ----------------
__global__ __launch_bounds__(256) void k_prefilter(const uint32_t* __restrict__ bth,
                                                   int* __restrict__ svcnt,
                                                   uint2* __restrict__ svrec) {
    int c = blockIdx.x * 256 + threadIdx.x;   // 289*256 == CCLS exactly
    int k0 = blockIdx.y * (KSMP / ROWG);
    uint32_t th = bth[c];
    uint32_t i = (uint32_t)k0 * (uint32_t)CCLS + (uint32_t)c;
#pragma unroll 4
    for (int kk = 0; kk < KSMP / ROWG; ++kk) {
        uint32_t bits = tf_bits(i);
        if (__builtin_expect(bits >= th, 0)) {
            int row = k0 + kk;
            int idx = atomicAdd(&svcnt[row], 1);
            if (idx < SVCAP) svrec[row * SVCAP + idx] = make_uint2((uint32_t)c, bits);
        }
        i += (uint32_t)CCLS;
    }
}

// ---------------- K3f: per-row exact eval + argmax (fallback: full scan) ----------------
__global__ __launch_bounds__(256) void k_finalize(const float* __restrict__ logits,
                                                  const int* __restrict__ svcnt,
                                                  const uint2* __restrict__ svrec,
                                                  int* __restrict__ samples) {
    int k = blockIdx.x;
    int tid = threadIdx.x;
    int n = svcnt[k];
    float best = -INFINITY; int bc = 0x7fffffff;
    if (n > 0 && n <= SVCAP) {
        if (tid < n) {
            uint2 rec = svrec[k * SVCAP + tid];
            int c = (int)rec.x;
            best = __fadd_rn(gumbel_from_u(uniform_from_bits(rec.y)), logits[c]);
            bc = c;
        }
    } else {
        // empty (P ~ e^-21) or overflow (Poisson(21) tail @64): exact full scan
        uint32_t base = (uint32_t)k * (uint32_t)CCLS;
        for (int c = tid; c < CCLS; c += 256) {
            float v = __fadd_rn(gumbel_from_u(uniform_from_bits(tf_bits(base + (uint32_t)c))), logits[c]);
            if (v > best || (v == best && c < bc)) { best = v; bc = c; }
        }
    }
    __shared__ float sv[256];
    __shared__ int   si[256];
    sv[tid] = best; si[tid] = bc; __syncthreads();
    for (int off = 128; off > 0; off >>= 1) {
        if (tid < off) {
            float v2 = sv[tid+off]; int i2 = si[tid+off];
            if (v2 > sv[tid] || (v2 == sv[tid] && i2 < si[tid])) { sv[tid] = v2; si[tid] = i2; }
        }
        __syncthreads();
    }
    if (tid == 0) samples[k] = si[0];
}

// ---------------- K3b: build sampled-cell hash table (single block) ----------------
__global__ __launch_bounds__(256) void k_build_table(const int* __restrict__ samples,
                                                     const int* __restrict__ yidx,
                                                     int* __restrict__ hkeys,
                                                     float* __restrict__ gsmall) {
    int tid = threadIdx.x;
    for (int j = tid; j < HSLOTS; j += 256) hkeys[j] = -1;
    for (int j = tid; j < 3*HSLOTS; j += 256) gsmall[j] = 0.0f;
    __syncthreads();
    for (int k = tid; k < KSMP; k += 256) {
        int s = samples[k];
        int xi = s / GZD, zi = s % GZD;
        int yi = yidx[s];
        int flat = (xi*GYD + yi)*GZD + zi;
        uint32_t h = cell_hash(flat);
        for (;;) {
            int prev = atomicCAS(&hkeys[h], -1, flat);
            if (prev == -1 || prev == flat) break;
            h = (h + 1) & (HSLOTS - 1);
        }
    }
}

// ---------------- K3c: replay votes, accumulate scale sums at sampled cells ----------------
__global__ __launch_bounds__(256) void k_scale_scatter(const float* __restrict__ pc, const float* __restrict__ xyz,
                          const float* __restrict__ scale, const float* __restrict__ prob,
                          const float* __restrict__ corners,
                          const int* __restrict__ hkeys, float* __restrict__ gsmall,
                          int N, RotTab rt) {
    __shared__ int lk[HSLOTS];
    for (int j = threadIdx.x; j < HSLOTS; j += 256) lk[j] = hkeys[j];
    __syncthreads();
    int i = blockIdx.x * blockDim.x + threadIdx.x;
    int r = blockIdx.y;
    if (i >= N) return;
    int flat;
    if (!vote_cell(pc[3*i], pc[3*i+1], pc[3*i+2], xyz[3*i], xyz[3*i+1], xyz[3*i+2],
                   rt.c[r], rt.s[r], corners[0], corners[1], corners[2], flat)) return;
    uint32_t h = cell_hash(flat);
    int slot = -1;
    for (;;) {
        int key = lk[h];
        if (key == flat) { slot = (int)h; break; }
        if (key == -1) break;
        h = (h + 1) & (HSLOTS - 1);
    }
    if (slot < 0) return;
    float w0 = prob[i];
    atomicAdd(&gsmall[3*slot+0], __fmul_rn(w0, scale[3*i]));
    atomicAdd(&gsmall[3*slot+1], __fmul_rn(w0, scale[3*i+1]));
    atomicAdd(&gsmall[3*slot+2], __fmul_rn(w0, scale[3*i+2]));
}

// ---------------- K4: one block per sample — world loc, scale, keep ----------------
__global__ __launch_bounds__(256) void k_post(const float* __restrict__ gobj,
                       const int* __restrict__ hkeys, const float* __restrict__ gsmall,
                       const int* __restrict__ yidx, const int* __restrict__ samples,
                       const float* __restrict__ corners, const float* __restrict__ vp, int M,
                       float* __restrict__ world, float* __restrict__ scv, int* __restrict__ keep) {
    int k = blockIdx.x;
    int tid = threadIdx.x;
    int s = samples[k];
    int xi = s / GZD, zi = s % GZD;
    int yi = yidx[s];
    float wx = __fadd_rn(__fmul_rn((float)xi, 0.03f), corners[0]);
    float wy = __fadd_rn(__fmul_rn((float)yi, 0.03f), corners[1]);
    float wz = __fadd_rn(__fmul_rn((float)zi, 0.03f), corners[2]);

    float dmin = INFINITY;
    for (int j = tid; j < M; j += 256) {
        float dx = __fsub_rn(wx, vp[3*j]);
        float dy = __fsub_rn(wy, vp[3*j+1]);
        float dz = __fsub_rn(wz, vp[3*j+2]);
        float sq = __fadd_rn(__fadd_rn(__fmul_rn(dx,dx), __fmul_rn(dy,dy)), __fmul_rn(dz,dz));
        dmin = fminf(dmin, __fsqrt_rn(sq));
    }
    __shared__ float sm[256];
    sm[tid] = dmin; __syncthreads();
    for (int off = 128; off > 0; off >>= 1) {
        if (tid < off) sm[tid] = fminf(sm[tid], sm[tid+off]);
        __syncthreads();
    }
    if (tid == 0) {
        world[3*k] = wx; world[3*k+1] = wy; world[3*k+2] = wz;
        int flat = (xi*GYD + yi)*GZD + zi;
        uint32_t h = cell_hash(flat);
        while (hkeys[h] != flat) h = (h + 1) & (HSLOTS - 1);  // guaranteed present
        float go = __fadd_rn(gobj[flat], 1e-7f);
        scv[3*k+0] = __fdiv_rn(gsmall[3*h+0], go);
        scv[3*k+1] = __fdiv_rn(gsmall[3*h+1], go);
        scv[3*k+2] = __fdiv_rn(gsmall[3*h+2], go);
        keep[k] = (sm[0] < 0.3f) ? 1 : 0;
    }
}

// ---------------- K5: stable 0/1 selection via parallel prefix-sum ----------------
__global__ __launch_bounds__(256) void k_select(const float* __restrict__ world,
                                                const float* __restrict__ scv,
                                                const int* __restrict__ keep,
                                                float* __restrict__ out) {
    __shared__ int kp[KSMP];
    __shared__ int tsum[256];
    __shared__ int sel[NPROP];
    __shared__ int anyk;
    int tid = threadIdx.x;
    if (tid == 0) anyk = 0;
    __syncthreads();
    int a = 0;
    for (int j = tid; j < KSMP; j += 256) { int v = keep[j]; kp[j] = v; a |= v; }
    if (a) anyk = 1;           // benign race, all writers store 1
    __syncthreads();
    int any = anyk;
    // kval[j] = any ? kp[j] : 1  (keep.any()==0 -> all ones -> identity order)
    int j0 = tid * 4;
    int k0v = any ? kp[j0]   : 1;
    int k1v = any ? kp[j0+1] : 1;
    int k2v = any ? kp[j0+2] : 1;
    int k3v = any ? kp[j0+3] : 1;
    int s0 = k0v, s1 = s0 + k1v, s2 = s1 + k2v, s3 = s2 + k3v;
    tsum[tid] = s3;
    __syncthreads();
    // Hillis-Steele inclusive scan over 256 thread-sums
    for (int off = 1; off < 256; off <<= 1) {
        int x = tsum[tid];
        if (tid >= off) x += tsum[tid - off];
        __syncthreads();
        tsum[tid] = x;
        __syncthreads();
    }
    int base = (tid > 0) ? tsum[tid-1] : 0;
    int nk = tsum[255];  // total kept
    // placement: kept j -> rank-1; unkept j -> nk + (j - rank)
    int inc[4] = { base + s0, base + s1, base + s2, base + s3 };
    int kv[4]  = { k0v, k1v, k2v, k3v };
    for (int q = 0; q < 4; ++q) {
        int j = j0 + q;
        int slot = kv[q] ? (inc[q] - 1) : (nk + j - inc[q]);
        if (slot < NPROP) sel[slot] = j;
    }
    __syncthreads();
    if (tid < NPROP) {
        int sidx = sel[tid];
        out[3*tid+0] = world[3*sidx+0];
        out[3*tid+1] = world[3*sidx+1];
        out[3*tid+2] = world[3*sidx+2];
        out[3*NPROP + tid] = 0.0f;                 // probs
        out[4*NPROP + 3*tid + 0] = scv[3*sidx+0];
        out[4*NPROP + 3*tid + 1] = scv[3*sidx+1];
        out[4*NPROP + 3*tid + 2] = scv[3*sidx+2];
    }
}

extern "C" void kernel_launch(void* const* d_in, const int* in_sizes, int n_in,
                              void* d_out, int out_size, void* d_ws, size_t ws_size,
                              hipStream_t stream) {
    const float* pc      = (const float*)d_in[0];
    const float* xyz     = (const float*)d_in[1];
    const float* scale   = (const float*)d_in[2];
    const float* prob    = (const float*)d_in[3];
    const float* corners = (const float*)d_in[4];
    const float* vp      = (const float*)d_in[5];
    int N = in_sizes[0] / 3;
    int M = in_sizes[5] / 3;
    int NV = N * NROT;

    const size_t G = (size_t)GXD * GYD * GZD;  // 8,286,208
    float* gobj    = (float*)d_ws;
    float* sumdist = gobj + G;              // 1 float   — zeroed below
    int*   bincnt  = (int*)(sumdist + 1);   // NBINS     — zeroed below
    int*   svcnt   = bincnt + NBINS;        // KSMP      — zeroed below
    int*   binbase = svcnt + KSMP;
    int*   bincur  = binbase + NBINS;
    float* logits  = (float*)(bincur + NBINS);
    uint32_t* bth  = (uint32_t*)(logits + CCLS);
    int*   yidx    = (int*)(bth + CCLS);
    int*   samples = yidx + CCLS;
    int*   hkeys   = samples + KSMP;
    float* gsmall  = (float*)(hkeys + HSLOTS);
    float* world   = gsmall + 3*HSLOTS;
    float* scv     = world + 3*KSMP;
    int*   keep    = (int*)(scv + 3*KSMP);
    uint2* svrec   = (uint2*)(((uintptr_t)(keep + KSMP) + 15) & ~(uintptr_t)15);
    int*   vflat   = (int*)(svrec + (size_t)KSMP * SVCAP);
    float* vw      = (float*)(vflat + NV);
    size_t need = (size_t)((char*)(vw + NV) - (char*)d_ws);
    if (ws_size < need) {
        fprintf(stderr, "kernel_launch: ws_size %zu < needed %zu\n", ws_size, need);
        return;
    }

    // zero sumdist + bincnt + svcnt (contiguous; gobj fully written by k_accum)
    hipMemsetAsync(sumdist, 0, (1 + NBINS + KSMP)*sizeof(int), stream);

    // rotation table: f32 theta chain exactly as reference, cos/sin in double -> f32
    RotTab rt;
    const float twopi = (float)(2.0 * M_PI);
    for (int r = 0; r < NROT; ++r) {
        float th = (twopi * (float)r) / 36.0f;
        rt.c[r] = (float)cos((double)th);
        rt.s[r] = (float)sin((double)th);
    }

    int pblocks = (N + 255) / 256;
    k_count<<<pblocks, 256, 0, stream>>>(pc, xyz, corners, N, rt, bincnt);
    k_prefix<<<1, 576, 0, stream>>>(bincnt, binbase, bincur);
    k_binwrite<<<pblocks, 256, 0, stream>>>(pc, xyz, prob, corners, N, rt, bincur, vflat, vw);
    k_accum<<<NBINS, 256, 0, stream>>>(binbase, bincnt, vflat, vw, gobj);
    k_colmax<<<(CCLS + 255) / 256, 256, 0, stream>>>(gobj, logits, yidx, sumdist);
    k_thresh<<<(CCLS + 255) / 256, 256, 0, stream>>>(logits, sumdist, bth);
    dim3 pf_grid(CCLS / 256, ROWG);
    k_prefilter<<<pf_grid, 256, 0, stream>>>(bth, svcnt, svrec);
    k_finalize<<<KSMP, 256, 0, stream>>>(logits, svcnt, svrec, samples);
    k_build_table<<<1, 256, 0, stream>>>(samples, yidx, hkeys, gsmall);
    dim3 sgrid(pblocks, NROT);
    k_scale_scatter<<<sgrid, 256, 0, stream>>>(pc, xyz, scale, prob, corners, hkeys, gsmall, N, rt);
    k_post<<<KSMP, 256, 0, stream>>>(gobj, hkeys, gsmall, yidx, samples, corners, vp, M, world, scv, keep);
    k_select<<<1, 256, 0, stream>>>(world, scv, keep, (float*)d_out);
}